// Round 6
// baseline (253.108 us; speedup 1.0000x reference)
//
#include <hip/hip_runtime.h>

// Problem constants
#define NNODES  50000
#define D       128
#define E       32
#define NMP     3
#define DEG     32
#define NEDGE   200000
#define B       1024
#define NC      8
#define S       16

#define RPM      17408   // rows per mp in L0 row space (16384 level-1 + 1024 level-0)
#define NKT      9       // K tiles of 32 (K=288)
#define WSTRIDE  36864   // ushorts per (mp,lay) feat-weight block: 9*4*128*8
#define WESTRIDE 9216    // ushorts per mp edge-weight block: 9*4*32*8

#define CONV_TASKS (1600000 + 6 * WSTRIDE + 3 * WESTRIDE)   // 1,848,832
#define TOT_TASKS  (CONV_TASKS + 3 * RPM)                    // 1,901,056 = 7426*256

typedef float f4 __attribute__((ext_vector_type(4)));
typedef short bh8 __attribute__((ext_vector_type(8)));   // 8 bf16 in 4 VGPRs

static __device__ __forceinline__ unsigned short f2bf(float f) {
    unsigned int u = __float_as_uint(f);
    u = u + 0x7FFFu + ((u >> 16) & 1u);   // RN-even
    return (unsigned short)(u >> 16);
}
static __device__ __forceinline__ float bf2f(unsigned short h) {
    return __uint_as_float(((unsigned int)h) << 16);
}

// ---------- fused one-shot conversion + level-1 sampling ----------
// B-fragment order: dst[((kt*4+q)*N + n)*8 + j] = W[k = kt*32+q*8+j][n]
__global__ __launch_bounds__(256) void convsamp_k(
    const float* __restrict__ feats, const float* __restrict__ Ws,
    const float* __restrict__ Wn, const float* __restrict__ We,
    const int* __restrict__ ids, const int* __restrict__ adjn,
    const int* __restrict__ adje,
    unsigned short* __restrict__ fb, unsigned short* __restrict__ WT0,
    unsigned short* __restrict__ WTe, int* __restrict__ gx, int* __restrict__ eid1)
{
    int i = blockIdx.x * 256 + threadIdx.x;
    if (i < 1600000) {                          // feats: 50000*128/4 float4 tasks
        float4 v = ((const float4*)feats)[i];
        unsigned int p0 = (unsigned int)f2bf(v.x) | ((unsigned int)f2bf(v.y) << 16);
        unsigned int p1 = (unsigned int)f2bf(v.z) | ((unsigned int)f2bf(v.w) << 16);
        ((uint2*)fb)[i] = make_uint2(p0, p1);
    } else if (i < 1600000 + 6 * WSTRIDE) {     // feat weights: [mp][lay] K=288 (Ws||Wn), N=128
        int i2 = i - 1600000;
        int ml = i2 / WSTRIDE, e = i2 % WSTRIDE;
        int j = e & 7, t1 = e >> 3;
        int n = t1 & 127, t2 = t1 >> 7;
        int q = t2 & 3, kt = t2 >> 2;
        int k = kt * 32 + q * 8 + j;
        float v = (k < 128) ? Ws[((size_t)ml * 128 + k) * 128 + n]
                            : Wn[((size_t)ml * 160 + (k - 128)) * 128 + n];
        WT0[(size_t)ml * WSTRIDE + e] = f2bf(v);
    } else if (i < CONV_TASKS) {                // edge weights: [mp][lay0] K=288,N=32
        int i3 = i - 1600000 - 6 * WSTRIDE;
        int mp = i3 / WESTRIDE, e = i3 % WESTRIDE;
        int j = e & 7, t1 = e >> 3;
        int n = t1 & 31, t2 = t1 >> 5;
        int q = t2 & 3, kt = t2 >> 2;
        int k = kt * 32 + q * 8 + j;
        float v = We[(((size_t)mp * 2) * 288 + k) * 32 + n];
        WTe[(size_t)mp * WESTRIDE + e] = f2bf(v);
    } else if (i < TOT_TASKS) {                 // sampling: 3*RPM tasks
        int i4 = i - CONV_TASKS;
        int mp = i4 / RPM, r = i4 % RPM;
        if (r < 16384) {
            int node = ids[r >> 4];
            gx[mp * RPM + r]   = adjn[((size_t)mp * NNODES + node) * DEG + (r & 15)];
            eid1[mp * 16384 + r] = adje[((size_t)mp * NNODES + node) * DEG + (r & 15)];
        } else {
            gx[mp * RPM + r] = ids[r - 16384];
        }
    }
}

// ---------- gather-mean -> nin [mp][RPM][160] bf16 ----------
// One wave per row; wave-uniform index bases; indices via readfirstlane (SGPRs,
// no LDS promotion); all 24 gathers issued straight-line (full MLP).
__global__ __launch_bounds__(256) void aggnin_k(
    const unsigned short* __restrict__ fb, const float* __restrict__ edge_emb,
    const int* __restrict__ adjn, const int* __restrict__ adje,
    const int* __restrict__ gx, const int* __restrict__ eid1,
    unsigned short* __restrict__ nin)
{
    const int mp = blockIdx.y;
    const int r = blockIdx.x * 4 + (threadIdx.x >> 6);   // < 17408, wave-uniform
    const int t = threadIdx.x & 63;
    const float* ee = edge_emb + (size_t)mp * NEDGE * E;

    const int* ip;    // 16 neighbor node ids (wave-uniform base)
    const int* eix;   // 16 edge ids (wave-uniform base)
    if (r < 16384) {
        int node = __builtin_amdgcn_readfirstlane(gx[mp * RPM + r]);
        ip  = adjn + ((size_t)mp * NNODES + node) * DEG;
        eix = adje + ((size_t)mp * NNODES + node) * DEG;
    } else {
        ip  = gx + mp * RPM + (r - 16384) * S;
        eix = eid1 + mp * 16384 + (r - 16384) * S;
    }

    const int hi = t >> 5, t31 = t & 31;

    unsigned int fv[S];
#pragma unroll
    for (int j = 0; j < S; ++j) {
        int nb = __builtin_amdgcn_readfirstlane(ip[j]);
        fv[j] = ((const unsigned int*)fb)[(size_t)nb * 64 + t];
    }
    float ev[S / 2];
#pragma unroll
    for (int e = 0; e < S / 2; ++e) {
        int e_ev = __builtin_amdgcn_readfirstlane(eix[2 * e]);
        int e_od = __builtin_amdgcn_readfirstlane(eix[2 * e + 1]);
        int edd = hi ? e_od : e_ev;
        ev[e] = ee[(size_t)edd * E + t31];
    }

    float s0 = 0.f, s1 = 0.f, se = 0.f;
#pragma unroll
    for (int j = 0; j < S; ++j) {
        s0 += bf2f((unsigned short)(fv[j] & 0xFFFF));
        s1 += bf2f((unsigned short)(fv[j] >> 16));
    }
#pragma unroll
    for (int e = 0; e < S / 2; ++e) se += ev[e];
    se += __shfl_xor(se, 32);

    const float inv = 1.0f / (float)S;
    unsigned short* row = nin + ((size_t)mp * RPM + r) * 160;
    ((unsigned int*)row)[t] =
        (unsigned int)f2bf(s0 * inv) | ((unsigned int)f2bf(s1 * inv) << 16);
    if (t < E) row[128 + t] = f2bf(se * inv);
}

// ---------- MFMA feat GEMM layer 0: fout = relu(A @ [Ws;Wn]), K=288, N=128 ----------
__global__ __launch_bounds__(256) void gemm_feat_k(
    const unsigned short* __restrict__ fb, const int* __restrict__ gx,
    const unsigned short* __restrict__ nin,
    const unsigned short* __restrict__ WT0,
    unsigned short* __restrict__ outb)
{
    const int mp = blockIdx.y;
    const int w = threadIdx.x >> 6;
    const int l = threadIdx.x & 63;
    const int q = l >> 4, lm = l & 15;
    const int m0 = blockIdx.x * 128 + w * 32;          // wave: 2 m-tiles (32 rows)
    const unsigned short* wb = WT0 + (size_t)mp * 2 * WSTRIDE;   // layer 0

    const unsigned short* ap[2];
    const unsigned short* np[2];
#pragma unroll
    for (int mt = 0; mt < 2; ++mt) {
        int row = m0 + mt * 16 + lm;
        int node = gx[mp * RPM + row];
        ap[mt] = fb + (size_t)node * 128;
        np[mt] = nin + ((size_t)mp * RPM + row) * 160;
    }

    f4 acc[2][8];
#pragma unroll
    for (int mt = 0; mt < 2; ++mt)
#pragma unroll
        for (int nt = 0; nt < 8; ++nt) acc[mt][nt] = (f4){0.f, 0.f, 0.f, 0.f};

#pragma unroll
    for (int kt = 0; kt < NKT; ++kt) {
        const int k0 = kt * 32 + q * 8;
        bh8 a[2];
#pragma unroll
        for (int mt = 0; mt < 2; ++mt) {
            const unsigned short* p = (k0 < 128) ? (ap[mt] + k0) : (np[mt] + (k0 - 128));
            a[mt] = *(const bh8*)p;
        }
        const unsigned short* wrow = wb + ((size_t)(kt * 4 + q) * 128 + lm) * 8;
#pragma unroll
        for (int nt = 0; nt < 8; ++nt) {
            bh8 bf = *(const bh8*)(wrow + nt * 16 * 8);
#pragma unroll
            for (int mt = 0; mt < 2; ++mt)
                acc[mt][nt] = __builtin_amdgcn_mfma_f32_16x16x32_bf16(a[mt], bf, acc[mt][nt], 0, 0, 0);
        }
    }

#pragma unroll
    for (int mt = 0; mt < 2; ++mt)
#pragma unroll
        for (int nt = 0; nt < 8; ++nt)
#pragma unroll
            for (int rr = 0; rr < 4; ++rr) {
                int row = m0 + mt * 16 + q * 4 + rr;   // C/D: col=lane&15, row=quad*4+reg
                int col = nt * 16 + lm;
                outb[((size_t)mp * RPM + row) * 128 + col] = f2bf(fmaxf(acc[mt][nt][rr], 0.f));
            }
}

// ---------- fused edge GEMM + layer-1 mean -> agg1 [mp][B][160] bf16 ----------
// Edge rows never materialized: segment mean taken from MFMA accumulators.
__global__ __launch_bounds__(256) void edgeagg_k(
    const unsigned short* __restrict__ fout, const float* __restrict__ edge_emb,
    const int* __restrict__ eid1, const unsigned short* __restrict__ WTe,
    unsigned short* __restrict__ agg1)
{
    const int mp = blockIdx.y;
    const int w = threadIdx.x >> 6, l = threadIdx.x & 63;
    const int q = l >> 4, lm = l & 15;
    const int m0 = blockIdx.x * 128 + w * 32;          // wave: 2 m-tiles = 2 segments
    const unsigned short* we = WTe + (size_t)mp * WESTRIDE;
    const unsigned short* f1base = fout + (size_t)mp * RPM * 128;
    const unsigned short* f0base = fout + ((size_t)mp * RPM + 16384) * 128;
    const float* ee = edge_emb + (size_t)mp * NEDGE * E;
    const float inv = 1.0f / (float)S;

    const unsigned short* a1p[2];
    const unsigned short* a0p[2];
    int eidL[2];
#pragma unroll
    for (int mt = 0; mt < 2; ++mt) {
        int row = m0 + mt * 16 + lm;
        a1p[mt] = f1base + (size_t)row * 128;
        a0p[mt] = f0base + (size_t)(row >> 4) * 128;
        eidL[mt] = eid1[mp * 16384 + row];
    }

    f4 acc[2][2];
#pragma unroll
    for (int mt = 0; mt < 2; ++mt) { acc[mt][0] = (f4){0,0,0,0}; acc[mt][1] = (f4){0,0,0,0}; }

#pragma unroll
    for (int kt = 0; kt < NKT; ++kt) {
        const int k0 = kt * 32 + q * 8;
        bh8 a[2];
#pragma unroll
        for (int mt = 0; mt < 2; ++mt) {
            if (kt < 4) {
                a[mt] = *(const bh8*)(a0p[mt] + k0);
            } else if (kt < 8) {
                a[mt] = *(const bh8*)(a1p[mt] + (k0 - 128));
            } else {
                const float* ep = ee + (size_t)eidL[mt] * E + q * 8;
                float4 v0 = *(const float4*)ep;
                float4 v1 = *(const float4*)(ep + 4);
                bh8 tv;
                tv[0] = (short)f2bf(v0.x); tv[1] = (short)f2bf(v0.y);
                tv[2] = (short)f2bf(v0.z); tv[3] = (short)f2bf(v0.w);
                tv[4] = (short)f2bf(v1.x); tv[5] = (short)f2bf(v1.y);
                tv[6] = (short)f2bf(v1.z); tv[7] = (short)f2bf(v1.w);
                a[mt] = tv;
            }
        }
        const unsigned short* wrow = we + ((size_t)(kt * 4 + q) * 32 + lm) * 8;
        bh8 b0 = *(const bh8*)(wrow);
        bh8 b1 = *(const bh8*)(wrow + 16 * 8);
#pragma unroll
        for (int mt = 0; mt < 2; ++mt) {
            acc[mt][0] = __builtin_amdgcn_mfma_f32_16x16x32_bf16(a[mt], b0, acc[mt][0], 0, 0, 0);
            acc[mt][1] = __builtin_amdgcn_mfma_f32_16x16x32_bf16(a[mt], b1, acc[mt][1], 0, 0, 0);
        }
    }

    // edge part of agg1: mean over the 16 rows of each m-tile (one segment)
#pragma unroll
    for (int mt = 0; mt < 2; ++mt) {
        int seg = (m0 >> 4) + mt;                       // global segment < 16384/16*... in [0,1024)
#pragma unroll
        for (int nt = 0; nt < 2; ++nt) {
            float ps = 0.f;
#pragma unroll
            for (int rr = 0; rr < 4; ++rr) ps += fmaxf(acc[mt][nt][rr], 0.f);
            ps += __shfl_xor(ps, 16);
            ps += __shfl_xor(ps, 32);                   // sum over quads -> full column sum
            if (l < 16)
                agg1[((size_t)mp * B + seg) * 160 + 128 + nt * 16 + lm] = f2bf(ps * inv);
        }
    }

    // f1 part of agg1: mean of fout level-1 rows for this wave's 2 segments
#pragma unroll
    for (int mt = 0; mt < 2; ++mt) {
        int seg = (m0 >> 4) + mt;
        const unsigned short* fr = f1base + (size_t)seg * 16 * 128;
        float s0 = 0.f, s1 = 0.f;
#pragma unroll
        for (int j = 0; j < S; ++j) {
            unsigned int u = ((const unsigned int*)(fr + j * 128))[l];
            s0 += bf2f((unsigned short)(u & 0xFFFF));
            s1 += bf2f((unsigned short)(u >> 16));
        }
        ((unsigned int*)(agg1 + ((size_t)mp * B + seg) * 160))[l] =
            (unsigned int)f2bf(s0 * inv) | ((unsigned int)f2bf(s1 * inv) << 16);
    }
}

// ---------- fused layer-1 GEMM (all 3 mps) + attention + normalize + fc ----------
// Block: 32 b-rows. LDS stages relu(GEMM) f32; then 8 threads/row finalize.
__global__ __launch_bounds__(256) void feat1fin_k(
    const unsigned short* __restrict__ fout, const unsigned short* __restrict__ agg1,
    const unsigned short* __restrict__ WT0,
    const float* __restrict__ attn, const float* __restrict__ fcw,
    const float* __restrict__ fcb, float* __restrict__ out)
{
    __shared__ float sbuf[NMP][32][132];                // +4 pad: conflict-free stores
    const int w = threadIdx.x >> 6, l = threadIdx.x & 63;
    const int q = l >> 4, lm = l & 15;
    const int m0 = blockIdx.x * 32;

    // tasks: (mp,mt) pairs; wave w does task w, waves 0,1 also task 4+w
    for (int task = w; task < 6; task += 4) {
        const int mp = task >> 1, mt = task & 1;
        const int row = m0 + mt * 16 + lm;              // < 1024
        const unsigned short* ap = fout + ((size_t)mp * RPM + 16384 + row) * 128;
        const unsigned short* np = agg1 + ((size_t)mp * B + row) * 160;
        const unsigned short* wb = WT0 + ((size_t)mp * 2 + 1) * WSTRIDE;

        f4 acc[8];
#pragma unroll
        for (int nt = 0; nt < 8; ++nt) acc[nt] = (f4){0.f, 0.f, 0.f, 0.f};
#pragma unroll
        for (int kt = 0; kt < NKT; ++kt) {
            const int k0 = kt * 32 + q * 8;
            bh8 a = (k0 < 128) ? *(const bh8*)(ap + k0) : *(const bh8*)(np + (k0 - 128));
            const unsigned short* wrow = wb + ((size_t)(kt * 4 + q) * 128 + lm) * 8;
#pragma unroll
            for (int nt = 0; nt < 8; ++nt) {
                bh8 bf = *(const bh8*)(wrow + nt * 16 * 8);
                acc[nt] = __builtin_amdgcn_mfma_f32_16x16x32_bf16(a, bf, acc[nt], 0, 0, 0);
            }
        }
#pragma unroll
        for (int nt = 0; nt < 8; ++nt)
#pragma unroll
            for (int rr = 0; rr < 4; ++rr)
                sbuf[mp][mt * 16 + q * 4 + rr][nt * 16 + lm] = fmaxf(acc[nt][rr], 0.f);
    }
    __syncthreads();

    // finalize: 8 threads per row, 16 dims each
    const int row = threadIdx.x >> 3;                   // [0,32)
    const int j = threadIdx.x & 7;
    const int d0 = j * 16;
    float sc[NMP];
#pragma unroll
    for (int mp = 0; mp < NMP; ++mp) {
        float p = 0.f;
#pragma unroll
        for (int d = 0; d < 16; ++d) p += sbuf[mp][row][d0 + d] * attn[d0 + d];
        p += __shfl_xor(p, 1); p += __shfl_xor(p, 2); p += __shfl_xor(p, 4);
        sc[mp] = tanhf(p);
    }
    float mx = fmaxf(sc[0], fmaxf(sc[1], sc[2]));
    float e0 = expf(sc[0] - mx), e1 = expf(sc[1] - mx), e2 = expf(sc[2] - mx);
    float isum = 1.f / (e0 + e1 + e2);
    float b0 = e0 * isum, b1 = e1 * isum, b2 = e2 * isum;

    float emb[16];
    float nn = 0.f;
#pragma unroll
    for (int d = 0; d < 16; ++d) {
        float v = b0 * sbuf[0][row][d0 + d] + b1 * sbuf[1][row][d0 + d]
                + b2 * sbuf[2][row][d0 + d];
        emb[d] = v;
        nn += v * v;
    }
    nn += __shfl_xor(nn, 1); nn += __shfl_xor(nn, 2); nn += __shfl_xor(nn, 4);
    float innorm = 1.f / fmaxf(sqrtf(nn), 1e-12f);
#pragma unroll
    for (int d = 0; d < 16; ++d) emb[d] *= innorm;

#pragma unroll
    for (int c = 0; c < NC; ++c) {
        float p = 0.f;
#pragma unroll
        for (int d = 0; d < 16; ++d) p += emb[d] * fcw[(d0 + d) * NC + c];
        p += __shfl_xor(p, 1); p += __shfl_xor(p, 2); p += __shfl_xor(p, 4);
        if (j == c) out[(size_t)(m0 + row) * NC + c] = p + fcb[c];
    }
}

extern "C" void kernel_launch(void* const* d_in, const int* in_sizes, int n_in,
                              void* d_out, int out_size, void* d_ws, size_t ws_size,
                              hipStream_t stream) {
    const int* ids        = (const int*)d_in[0];
    const float* feats    = (const float*)d_in[1];
    const float* edge_emb = (const float*)d_in[2];
    const int* adjn       = (const int*)d_in[3];
    const int* adje       = (const int*)d_in[4];
    const float* Ws       = (const float*)d_in[5];
    const float* Wn       = (const float*)d_in[6];
    const float* We       = (const float*)d_in[7];
    const float* attn     = (const float*)d_in[8];
    const float* fcw      = (const float*)d_in[9];
    const float* fcb      = (const float*)d_in[10];
    float* out = (float*)d_out;

    // workspace layout (~44 MB; all regions fully written before read each call)
    char* p = (char*)d_ws;
    unsigned short* WT0 = (unsigned short*)p; p += (size_t)6 * WSTRIDE * 2;
    unsigned short* WTe = (unsigned short*)p; p += (size_t)3 * WESTRIDE * 2;
    unsigned short* fb  = (unsigned short*)p; p += (size_t)NNODES * 128 * 2;
    int* gx   = (int*)p;                      p += (size_t)3 * RPM * 4;
    int* eid1 = (int*)p;                      p += (size_t)3 * 16384 * 4;
    unsigned short* nin  = (unsigned short*)p; p += (size_t)3 * RPM * 160 * 2;
    unsigned short* fout = (unsigned short*)p; p += (size_t)3 * RPM * 128 * 2;
    unsigned short* agg1 = (unsigned short*)p; p += (size_t)3 * B * 160 * 2;

    convsamp_k<<<TOT_TASKS / 256, 256, 0, stream>>>(feats, Ws, Wn, We, ids, adjn, adje,
                                                    fb, WT0, WTe, gx, eid1);
    aggnin_k<<<dim3(RPM / 4, 3), 256, 0, stream>>>(fb, edge_emb, adjn, adje, gx, eid1, nin);
    gemm_feat_k<<<dim3(136, 3), 256, 0, stream>>>(fb, gx, nin, WT0, fout);
    edgeagg_k<<<dim3(128, 3), 256, 0, stream>>>(fout, edge_emb, eid1, WTe, agg1);
    feat1fin_k<<<32, 256, 0, stream>>>(fout, agg1, WT0, attn, fcw, fcb, out);
}

// Round 7
// 242.865 us; speedup vs baseline: 1.0422x; 1.0422x over previous
//
#include <hip/hip_runtime.h>

// Problem constants
#define NNODES  50000
#define D       128
#define E       32
#define NMP     3
#define DEG     32
#define NEDGE   200000
#define B       1024
#define NC      8
#define S       16

#define RPM      17408   // rows per mp in L0 row space (16384 level-1 + 1024 level-0)
#define NKT      9       // K tiles of 32 (K=288)
#define WSTRIDE  36864   // ushorts per (mp,lay) feat-weight block: 9*4*128*8
#define WESTRIDE 9216    // ushorts per mp edge-weight block: 9*4*32*8

#define CONV_TASKS (1600000 + 6 * WSTRIDE + 3 * WESTRIDE)   // 1,848,832
#define TOT_TASKS  (CONV_TASKS + 3 * RPM)                    // 1,901,056 = 7426*256

typedef float f4 __attribute__((ext_vector_type(4)));
typedef short bh8 __attribute__((ext_vector_type(8)));   // 8 bf16 in 4 VGPRs

static __device__ __forceinline__ unsigned short f2bf(float f) {
    unsigned int u = __float_as_uint(f);
    u = u + 0x7FFFu + ((u >> 16) & 1u);   // RN-even
    return (unsigned short)(u >> 16);
}
static __device__ __forceinline__ float bf2f(unsigned short h) {
    return __uint_as_float(((unsigned int)h) << 16);
}

// ---------- fused one-shot conversion + level-1 sampling ----------
// B-fragment order: dst[((kt*4+q)*N + n)*8 + j] = W[k = kt*32+q*8+j][n]
__global__ __launch_bounds__(256) void convsamp_k(
    const float* __restrict__ feats, const float* __restrict__ Ws,
    const float* __restrict__ Wn, const float* __restrict__ We,
    const int* __restrict__ ids, const int* __restrict__ adjn,
    const int* __restrict__ adje,
    unsigned short* __restrict__ fb, unsigned short* __restrict__ WT0,
    unsigned short* __restrict__ WTe, int* __restrict__ gx, int* __restrict__ eid1)
{
    int i = blockIdx.x * 256 + threadIdx.x;
    if (i < 1600000) {                          // feats: 50000*128/4 float4 tasks
        float4 v = ((const float4*)feats)[i];
        unsigned int p0 = (unsigned int)f2bf(v.x) | ((unsigned int)f2bf(v.y) << 16);
        unsigned int p1 = (unsigned int)f2bf(v.z) | ((unsigned int)f2bf(v.w) << 16);
        ((uint2*)fb)[i] = make_uint2(p0, p1);
    } else if (i < 1600000 + 6 * WSTRIDE) {     // feat weights: [mp][lay] K=288 (Ws||Wn), N=128
        int i2 = i - 1600000;
        int ml = i2 / WSTRIDE, e = i2 % WSTRIDE;
        int j = e & 7, t1 = e >> 3;
        int n = t1 & 127, t2 = t1 >> 7;
        int q = t2 & 3, kt = t2 >> 2;
        int k = kt * 32 + q * 8 + j;
        float v = (k < 128) ? Ws[((size_t)ml * 128 + k) * 128 + n]
                            : Wn[((size_t)ml * 160 + (k - 128)) * 128 + n];
        WT0[(size_t)ml * WSTRIDE + e] = f2bf(v);
    } else if (i < CONV_TASKS) {                // edge weights: [mp][lay0] K=288,N=32
        int i3 = i - 1600000 - 6 * WSTRIDE;
        int mp = i3 / WESTRIDE, e = i3 % WESTRIDE;
        int j = e & 7, t1 = e >> 3;
        int n = t1 & 31, t2 = t1 >> 5;
        int q = t2 & 3, kt = t2 >> 2;
        int k = kt * 32 + q * 8 + j;
        float v = We[(((size_t)mp * 2) * 288 + k) * 32 + n];
        WTe[(size_t)mp * WESTRIDE + e] = f2bf(v);
    } else if (i < TOT_TASKS) {                 // sampling: 3*RPM tasks
        int i4 = i - CONV_TASKS;
        int mp = i4 / RPM, r = i4 % RPM;
        if (r < 16384) {
            int node = ids[r >> 4];
            gx[mp * RPM + r]     = adjn[((size_t)mp * NNODES + node) * DEG + (r & 15)];
            eid1[mp * 16384 + r] = adje[((size_t)mp * NNODES + node) * DEG + (r & 15)];
        } else {
            gx[mp * RPM + r] = ids[r - 16384];
        }
    }
}

// ---------- fused gather-mean + layer-0 MFMA GEMM -> fout [mp][RPM][128] bf16 ----------
// Block = 32 rows. Phase A: gather self-feats + neighbor/edge means into LDS
// (wave-uniform index bases, readfirstlane -> SGPRs, straight-line gathers).
// Phase B: fout = relu([A | nin] @ [Ws;Wn]) with A/nin read from LDS.
// LDS strides 136/168 bf16: only 2-way bank aliasing (free per m136).
__global__ __launch_bounds__(256) void aggfeat_k(
    const unsigned short* __restrict__ fb, const float* __restrict__ edge_emb,
    const int* __restrict__ adjn, const int* __restrict__ adje,
    const int* __restrict__ gx, const int* __restrict__ eid1,
    const unsigned short* __restrict__ WT0,
    unsigned short* __restrict__ fout)
{
    __shared__ unsigned short Asm[32][136];   // self feats (128 used), 68 words/row
    __shared__ unsigned short Nsm[32][168];   // nin rows (160 used), 84 words/row
    const int mp = blockIdx.y;
    const int w = threadIdx.x >> 6, t = threadIdx.x & 63;
    const int r0 = blockIdx.x * 32;
    const float* ee = edge_emb + (size_t)mp * NEDGE * E;
    const int hi = t >> 5, t31 = t & 31;
    const float inv = 1.0f / (float)S;

    // ---- phase A: wave w handles local rows w*8 .. w*8+7 ----
    for (int rr = 0; rr < 8; ++rr) {
        const int lr = w * 8 + rr;
        const int r = r0 + lr;
        const int self = __builtin_amdgcn_readfirstlane(gx[mp * RPM + r]);
        const int* ip;
        const int* eix;
        if (r < 16384) {
            ip  = adjn + ((size_t)mp * NNODES + self) * DEG;
            eix = adje + ((size_t)mp * NNODES + self) * DEG;
        } else {
            ip  = gx + mp * RPM + (r - 16384) * S;
            eix = eid1 + mp * 16384 + (r - 16384) * S;
        }
        // self-row + 16 neighbor gathers: 17 independent 256B coalesced loads
        unsigned int av = ((const unsigned int*)fb)[(size_t)self * 64 + t];
        unsigned int fv[S];
#pragma unroll
        for (int j = 0; j < S; ++j) {
            int nb = __builtin_amdgcn_readfirstlane(ip[j]);
            fv[j] = ((const unsigned int*)fb)[(size_t)nb * 64 + t];
        }
        // edge gathers: lanes 0-31 even neighbor, lanes 32-63 odd neighbor
        float ev[S / 2];
#pragma unroll
        for (int e = 0; e < S / 2; ++e) {
            int e_ev = __builtin_amdgcn_readfirstlane(eix[2 * e]);
            int e_od = __builtin_amdgcn_readfirstlane(eix[2 * e + 1]);
            int edd = hi ? e_od : e_ev;
            ev[e] = ee[(size_t)edd * E + t31];
        }
        float s0 = 0.f, s1 = 0.f, se = 0.f;
#pragma unroll
        for (int j = 0; j < S; ++j) {
            s0 += bf2f((unsigned short)(fv[j] & 0xFFFF));
            s1 += bf2f((unsigned short)(fv[j] >> 16));
        }
#pragma unroll
        for (int e = 0; e < S / 2; ++e) se += ev[e];
        se += __shfl_xor(se, 32);

        ((unsigned int*)&Asm[lr][0])[t] = av;
        ((unsigned int*)&Nsm[lr][0])[t] =
            (unsigned int)f2bf(s0 * inv) | ((unsigned int)f2bf(s1 * inv) << 16);
        if (t < E) Nsm[lr][128 + t] = f2bf(se * inv);
    }
    __syncthreads();

    // ---- phase B: wave w computes n-tiles {2w, 2w+1} for both m-tiles ----
    const int q = t >> 4, lm = t & 15;
    const unsigned short* wb = WT0 + (size_t)mp * 2 * WSTRIDE;   // layer 0

    f4 acc[2][2];
#pragma unroll
    for (int mt = 0; mt < 2; ++mt) { acc[mt][0] = (f4){0,0,0,0}; acc[mt][1] = (f4){0,0,0,0}; }

#pragma unroll
    for (int kt = 0; kt < NKT; ++kt) {
        const int k0 = kt * 32 + q * 8;
        bh8 a[2];
#pragma unroll
        for (int mt = 0; mt < 2; ++mt) {
            int lr = mt * 16 + lm;
            a[mt] = (k0 < 128) ? *(const bh8*)&Asm[lr][k0]
                               : *(const bh8*)&Nsm[lr][k0 - 128];
        }
        const unsigned short* wrow = wb + ((size_t)(kt * 4 + q) * 128 + lm) * 8;
#pragma unroll
        for (int ntl = 0; ntl < 2; ++ntl) {
            bh8 bf = *(const bh8*)(wrow + (w * 2 + ntl) * 16 * 8);
#pragma unroll
            for (int mt = 0; mt < 2; ++mt)
                acc[mt][ntl] = __builtin_amdgcn_mfma_f32_16x16x32_bf16(a[mt], bf, acc[mt][ntl], 0, 0, 0);
        }
    }

#pragma unroll
    for (int mt = 0; mt < 2; ++mt)
#pragma unroll
        for (int ntl = 0; ntl < 2; ++ntl)
#pragma unroll
            for (int rr = 0; rr < 4; ++rr) {
                int row = r0 + mt * 16 + q * 4 + rr;   // C/D: col=lane&15, row=quad*4+reg
                int col = (w * 2 + ntl) * 16 + lm;
                fout[((size_t)mp * RPM + row) * 128 + col] = f2bf(fmaxf(acc[mt][ntl][rr], 0.f));
            }
}

// ---------- fused edge GEMM + layer-1 mean -> agg1 [mp][B][160] bf16 ----------
// Edge rows never materialized: segment mean taken from MFMA accumulators.
__global__ __launch_bounds__(256) void edgeagg_k(
    const unsigned short* __restrict__ fout, const float* __restrict__ edge_emb,
    const int* __restrict__ eid1, const unsigned short* __restrict__ WTe,
    unsigned short* __restrict__ agg1)
{
    const int mp = blockIdx.y;
    const int w = threadIdx.x >> 6, l = threadIdx.x & 63;
    const int q = l >> 4, lm = l & 15;
    const int m0 = blockIdx.x * 128 + w * 32;          // wave: 2 m-tiles = 2 segments
    const unsigned short* we = WTe + (size_t)mp * WESTRIDE;
    const unsigned short* f1base = fout + (size_t)mp * RPM * 128;
    const unsigned short* f0base = fout + ((size_t)mp * RPM + 16384) * 128;
    const float* ee = edge_emb + (size_t)mp * NEDGE * E;
    const float inv = 1.0f / (float)S;

    const unsigned short* a1p[2];
    const unsigned short* a0p[2];
    int eidL[2];
#pragma unroll
    for (int mt = 0; mt < 2; ++mt) {
        int row = m0 + mt * 16 + lm;
        a1p[mt] = f1base + (size_t)row * 128;
        a0p[mt] = f0base + (size_t)(row >> 4) * 128;
        eidL[mt] = eid1[mp * 16384 + row];
    }

    f4 acc[2][2];
#pragma unroll
    for (int mt = 0; mt < 2; ++mt) { acc[mt][0] = (f4){0,0,0,0}; acc[mt][1] = (f4){0,0,0,0}; }

#pragma unroll
    for (int kt = 0; kt < NKT; ++kt) {
        const int k0 = kt * 32 + q * 8;
        bh8 a[2];
#pragma unroll
        for (int mt = 0; mt < 2; ++mt) {
            if (kt < 4) {
                a[mt] = *(const bh8*)(a0p[mt] + k0);
            } else if (kt < 8) {
                a[mt] = *(const bh8*)(a1p[mt] + (k0 - 128));
            } else {
                const float* ep = ee + (size_t)eidL[mt] * E + q * 8;
                float4 v0 = *(const float4*)ep;
                float4 v1 = *(const float4*)(ep + 4);
                bh8 tv;
                tv[0] = (short)f2bf(v0.x); tv[1] = (short)f2bf(v0.y);
                tv[2] = (short)f2bf(v0.z); tv[3] = (short)f2bf(v0.w);
                tv[4] = (short)f2bf(v1.x); tv[5] = (short)f2bf(v1.y);
                tv[6] = (short)f2bf(v1.z); tv[7] = (short)f2bf(v1.w);
                a[mt] = tv;
            }
        }
        const unsigned short* wrow = we + ((size_t)(kt * 4 + q) * 32 + lm) * 8;
        bh8 b0 = *(const bh8*)(wrow);
        bh8 b1 = *(const bh8*)(wrow + 16 * 8);
#pragma unroll
        for (int mt = 0; mt < 2; ++mt) {
            acc[mt][0] = __builtin_amdgcn_mfma_f32_16x16x32_bf16(a[mt], b0, acc[mt][0], 0, 0, 0);
            acc[mt][1] = __builtin_amdgcn_mfma_f32_16x16x32_bf16(a[mt], b1, acc[mt][1], 0, 0, 0);
        }
    }

    // edge part of agg1: mean over the 16 rows of each m-tile (one segment)
#pragma unroll
    for (int mt = 0; mt < 2; ++mt) {
        int seg = (m0 >> 4) + mt;
#pragma unroll
        for (int nt = 0; nt < 2; ++nt) {
            float ps = 0.f;
#pragma unroll
            for (int rr = 0; rr < 4; ++rr) ps += fmaxf(acc[mt][nt][rr], 0.f);
            ps += __shfl_xor(ps, 16);
            ps += __shfl_xor(ps, 32);                   // sum over quads -> full column sum
            if (l < 16)
                agg1[((size_t)mp * B + seg) * 160 + 128 + nt * 16 + lm] = f2bf(ps * inv);
        }
    }

    // f1 part of agg1: mean of fout level-1 rows for this wave's 2 segments
#pragma unroll
    for (int mt = 0; mt < 2; ++mt) {
        int seg = (m0 >> 4) + mt;
        const unsigned short* fr = f1base + (size_t)seg * 16 * 128;
        float s0 = 0.f, s1 = 0.f;
#pragma unroll
        for (int j = 0; j < S; ++j) {
            unsigned int u = ((const unsigned int*)(fr + j * 128))[l];
            s0 += bf2f((unsigned short)(u & 0xFFFF));
            s1 += bf2f((unsigned short)(u >> 16));
        }
        ((unsigned int*)(agg1 + ((size_t)mp * B + seg) * 160))[l] =
            (unsigned int)f2bf(s0 * inv) | ((unsigned int)f2bf(s1 * inv) << 16);
    }
}

// ---------- fused layer-1 GEMM (all 3 mps) + attention + normalize + fc ----------
// Block: 32 b-rows. LDS stages relu(GEMM) f32; then 8 threads/row finalize.
__global__ __launch_bounds__(256) void feat1fin_k(
    const unsigned short* __restrict__ fout, const unsigned short* __restrict__ agg1,
    const unsigned short* __restrict__ WT0,
    const float* __restrict__ attn, const float* __restrict__ fcw,
    const float* __restrict__ fcb, float* __restrict__ out)
{
    __shared__ float sbuf[NMP][32][132];                // +4 pad: conflict-free stores
    const int w = threadIdx.x >> 6, l = threadIdx.x & 63;
    const int q = l >> 4, lm = l & 15;
    const int m0 = blockIdx.x * 32;

    // tasks: (mp,mt) pairs; wave w does task w, waves 0,1 also task 4+w
    for (int task = w; task < 6; task += 4) {
        const int mp = task >> 1, mt = task & 1;
        const int row = m0 + mt * 16 + lm;              // < 1024
        const unsigned short* ap = fout + ((size_t)mp * RPM + 16384 + row) * 128;
        const unsigned short* np = agg1 + ((size_t)mp * B + row) * 160;
        const unsigned short* wb = WT0 + ((size_t)mp * 2 + 1) * WSTRIDE;

        f4 acc[8];
#pragma unroll
        for (int nt = 0; nt < 8; ++nt) acc[nt] = (f4){0.f, 0.f, 0.f, 0.f};
#pragma unroll
        for (int kt = 0; kt < NKT; ++kt) {
            const int k0 = kt * 32 + q * 8;
            bh8 a = (k0 < 128) ? *(const bh8*)(ap + k0) : *(const bh8*)(np + (k0 - 128));
            const unsigned short* wrow = wb + ((size_t)(kt * 4 + q) * 128 + lm) * 8;
#pragma unroll
            for (int nt = 0; nt < 8; ++nt) {
                bh8 bf = *(const bh8*)(wrow + nt * 16 * 8);
                acc[nt] = __builtin_amdgcn_mfma_f32_16x16x32_bf16(a, bf, acc[nt], 0, 0, 0);
            }
        }
#pragma unroll
        for (int nt = 0; nt < 8; ++nt)
#pragma unroll
            for (int rr = 0; rr < 4; ++rr)
                sbuf[mp][mt * 16 + q * 4 + rr][nt * 16 + lm] = fmaxf(acc[nt][rr], 0.f);
    }
    __syncthreads();

    // finalize: 8 threads per row, 16 dims each
    const int row = threadIdx.x >> 3;                   // [0,32)
    const int j = threadIdx.x & 7;
    const int d0 = j * 16;
    float sc[NMP];
#pragma unroll
    for (int mp = 0; mp < NMP; ++mp) {
        float p = 0.f;
#pragma unroll
        for (int d = 0; d < 16; ++d) p += sbuf[mp][row][d0 + d] * attn[d0 + d];
        p += __shfl_xor(p, 1); p += __shfl_xor(p, 2); p += __shfl_xor(p, 4);
        sc[mp] = tanhf(p);
    }
    float mx = fmaxf(sc[0], fmaxf(sc[1], sc[2]));
    float e0 = expf(sc[0] - mx), e1 = expf(sc[1] - mx), e2 = expf(sc[2] - mx);
    float isum = 1.f / (e0 + e1 + e2);
    float b0 = e0 * isum, b1 = e1 * isum, b2 = e2 * isum;

    float emb[16];
    float nn = 0.f;
#pragma unroll
    for (int d = 0; d < 16; ++d) {
        float v = b0 * sbuf[0][row][d0 + d] + b1 * sbuf[1][row][d0 + d]
                + b2 * sbuf[2][row][d0 + d];
        emb[d] = v;
        nn += v * v;
    }
    nn += __shfl_xor(nn, 1); nn += __shfl_xor(nn, 2); nn += __shfl_xor(nn, 4);
    float innorm = 1.f / fmaxf(sqrtf(nn), 1e-12f);
#pragma unroll
    for (int d = 0; d < 16; ++d) emb[d] *= innorm;

#pragma unroll
    for (int c = 0; c < NC; ++c) {
        float p = 0.f;
#pragma unroll
        for (int d = 0; d < 16; ++d) p += emb[d] * fcw[(d0 + d) * NC + c];
        p += __shfl_xor(p, 1); p += __shfl_xor(p, 2); p += __shfl_xor(p, 4);
        if (j == c) out[(size_t)(m0 + row) * NC + c] = p + fcb[c];
    }
}

extern "C" void kernel_launch(void* const* d_in, const int* in_sizes, int n_in,
                              void* d_out, int out_size, void* d_ws, size_t ws_size,
                              hipStream_t stream) {
    const int* ids        = (const int*)d_in[0];
    const float* feats    = (const float*)d_in[1];
    const float* edge_emb = (const float*)d_in[2];
    const int* adjn       = (const int*)d_in[3];
    const int* adje       = (const int*)d_in[4];
    const float* Ws       = (const float*)d_in[5];
    const float* Wn       = (const float*)d_in[6];
    const float* We       = (const float*)d_in[7];
    const float* attn     = (const float*)d_in[8];
    const float* fcw      = (const float*)d_in[9];
    const float* fcb      = (const float*)d_in[10];
    float* out = (float*)d_out;

    // workspace layout (~28 MB; all regions fully written before read each call)
    char* p = (char*)d_ws;
    unsigned short* WT0 = (unsigned short*)p; p += (size_t)6 * WSTRIDE * 2;
    unsigned short* WTe = (unsigned short*)p; p += (size_t)3 * WESTRIDE * 2;
    unsigned short* fb  = (unsigned short*)p; p += (size_t)NNODES * 128 * 2;
    int* gx   = (int*)p;                      p += (size_t)3 * RPM * 4;
    int* eid1 = (int*)p;                      p += (size_t)3 * 16384 * 4;
    unsigned short* fout = (unsigned short*)p; p += (size_t)3 * RPM * 128 * 2;
    unsigned short* agg1 = (unsigned short*)p; p += (size_t)3 * B * 160 * 2;

    convsamp_k<<<TOT_TASKS / 256, 256, 0, stream>>>(feats, Ws, Wn, We, ids, adjn, adje,
                                                    fb, WT0, WTe, gx, eid1);
    aggfeat_k<<<dim3(RPM / 32, 3), 256, 0, stream>>>(fb, edge_emb, adjn, adje, gx, eid1,
                                                     WT0, fout);
    edgeagg_k<<<dim3(128, 3), 256, 0, stream>>>(fout, edge_emb, eid1, WTe, agg1);
    feat1fin_k<<<32, 256, 0, stream>>>(fout, agg1, WT0, attn, fcw, fcb, out);
}

// Round 8
// 241.996 us; speedup vs baseline: 1.0459x; 1.0036x over previous
//
#include <hip/hip_runtime.h>

// Problem constants
#define NNODES  50000
#define D       128
#define E       32
#define NMP     3
#define DEG     32
#define NEDGE   200000
#define B       1024
#define NC      8
#define S       16

#define RPM      17408   // rows per mp in L0 row space (16384 level-1 + 1024 level-0)
#define NKT      9       // K tiles of 32 (K=288)
#define WSTRIDE  36864   // ushorts per (mp,lay) feat-weight block: 9*4*128*8
#define WESTRIDE 9216    // ushorts per mp edge-weight block: 9*4*32*8

#define CONV_TASKS (1600000 + 6 * WSTRIDE + 3 * WESTRIDE)   // 1,848,832
#define TOT_TASKS  (CONV_TASKS + 3 * RPM)                    // 1,901,056 = 7426*256

typedef float f4 __attribute__((ext_vector_type(4)));
typedef short bh8 __attribute__((ext_vector_type(8)));   // 8 bf16 in 4 VGPRs

static __device__ __forceinline__ unsigned short f2bf(float f) {
    unsigned int u = __float_as_uint(f);
    u = u + 0x7FFFu + ((u >> 16) & 1u);   // RN-even
    return (unsigned short)(u >> 16);
}
static __device__ __forceinline__ float bf2f(unsigned short h) {
    return __uint_as_float(((unsigned int)h) << 16);
}

// ---------- fused one-shot conversion + level-1 sampling ----------
// B-fragment order: dst[((kt*4+q)*N + n)*8 + j] = W[k = kt*32+q*8+j][n]
__global__ __launch_bounds__(256) void convsamp_k(
    const float* __restrict__ feats, const float* __restrict__ Ws,
    const float* __restrict__ Wn, const float* __restrict__ We,
    const int* __restrict__ ids, const int* __restrict__ adjn,
    const int* __restrict__ adje,
    unsigned short* __restrict__ fb, unsigned short* __restrict__ WT0,
    unsigned short* __restrict__ WTe, int* __restrict__ gx, int* __restrict__ eid1)
{
    int i = blockIdx.x * 256 + threadIdx.x;
    if (i < 1600000) {                          // feats: 50000*128/4 float4 tasks
        float4 v = ((const float4*)feats)[i];
        unsigned int p0 = (unsigned int)f2bf(v.x) | ((unsigned int)f2bf(v.y) << 16);
        unsigned int p1 = (unsigned int)f2bf(v.z) | ((unsigned int)f2bf(v.w) << 16);
        ((uint2*)fb)[i] = make_uint2(p0, p1);
    } else if (i < 1600000 + 6 * WSTRIDE) {     // feat weights: [mp][lay] K=288 (Ws||Wn), N=128
        int i2 = i - 1600000;
        int ml = i2 / WSTRIDE, e = i2 % WSTRIDE;
        int j = e & 7, t1 = e >> 3;
        int n = t1 & 127, t2 = t1 >> 7;
        int q = t2 & 3, kt = t2 >> 2;
        int k = kt * 32 + q * 8 + j;
        float v = (k < 128) ? Ws[((size_t)ml * 128 + k) * 128 + n]
                            : Wn[((size_t)ml * 160 + (k - 128)) * 128 + n];
        WT0[(size_t)ml * WSTRIDE + e] = f2bf(v);
    } else if (i < CONV_TASKS) {                // edge weights: [mp][lay0] K=288,N=32
        int i3 = i - 1600000 - 6 * WSTRIDE;
        int mp = i3 / WESTRIDE, e = i3 % WESTRIDE;
        int j = e & 7, t1 = e >> 3;
        int n = t1 & 31, t2 = t1 >> 5;
        int q = t2 & 3, kt = t2 >> 2;
        int k = kt * 32 + q * 8 + j;
        float v = We[(((size_t)mp * 2) * 288 + k) * 32 + n];
        WTe[(size_t)mp * WESTRIDE + e] = f2bf(v);
    } else if (i < TOT_TASKS) {                 // sampling: 3*RPM tasks
        int i4 = i - CONV_TASKS;
        int mp = i4 / RPM, r = i4 % RPM;
        if (r < 16384) {
            int node = ids[r >> 4];
            gx[mp * RPM + r]     = adjn[((size_t)mp * NNODES + node) * DEG + (r & 15)];
            eid1[mp * 16384 + r] = adje[((size_t)mp * NNODES + node) * DEG + (r & 15)];
        } else {
            gx[mp * RPM + r] = ids[r - 16384];
        }
    }
}

// ---------- fused gather-mean + layer-0 MFMA GEMM -> fout [mp][RPM][128] bf16 ----------
// Block = 16 rows (1 m-tile). Phase A: each wave handles 4 rows as 2 interleaved
// PAIRS — both rows' indices + all ~50 gathers issued straight-line before any
// use (2 serialization chains/wave instead of 8). Phase B: each wave computes
// 2 n-tiles of the m-tile from LDS. Small LDS (9.7 KB) -> several blocks/CU so
// phase A of one block overlaps phase B of another.
__global__ __launch_bounds__(256) void aggfeat_k(
    const unsigned short* __restrict__ fb, const float* __restrict__ edge_emb,
    const int* __restrict__ adjn, const int* __restrict__ adje,
    const int* __restrict__ gx, const int* __restrict__ eid1,
    const unsigned short* __restrict__ WT0,
    unsigned short* __restrict__ fout)
{
    __shared__ unsigned short Asm[16][136];   // self feats (128 used)
    __shared__ unsigned short Nsm[16][168];   // nin rows (160 used)
    const int mp = blockIdx.y;
    const int w = threadIdx.x >> 6, t = threadIdx.x & 63;
    const int r0 = blockIdx.x * 16;
    const float* ee = edge_emb + (size_t)mp * NEDGE * E;
    const int hi = t >> 5, t31 = t & 31;
    const float inv = 1.0f / (float)S;
    const unsigned int* fb32 = (const unsigned int*)fb;
    const int lvl1 = (r0 < 16384);            // block-uniform: whole tile same side

    // ---- phase A: wave w rows w*4 .. w*4+3, processed as 2 pairs ----
    for (int pp = 0; pp < 2; ++pp) {
        const int lra = w * 4 + pp * 2, lrb = lra + 1;
        const int ra = r0 + lra, rb = r0 + lrb;
        const int sa = __builtin_amdgcn_readfirstlane(gx[mp * RPM + ra]);
        const int sb = __builtin_amdgcn_readfirstlane(gx[mp * RPM + rb]);
        const int *ipa, *eixa, *ipb, *eixb;
        if (lvl1) {
            ipa  = adjn + ((size_t)mp * NNODES + sa) * DEG;
            eixa = adje + ((size_t)mp * NNODES + sa) * DEG;
            ipb  = adjn + ((size_t)mp * NNODES + sb) * DEG;
            eixb = adje + ((size_t)mp * NNODES + sb) * DEG;
        } else {
            ipa  = gx + mp * RPM + (ra - 16384) * S;
            eixa = eid1 + mp * 16384 + (ra - 16384) * S;
            ipb  = gx + mp * RPM + (rb - 16384) * S;
            eixb = eid1 + mp * 16384 + (rb - 16384) * S;
        }
        // issue ALL gathers for both rows before any use
        unsigned int ava = fb32[(size_t)sa * 64 + t];
        unsigned int avb = fb32[(size_t)sb * 64 + t];
        unsigned int fva[S], fvb[S];
#pragma unroll
        for (int j = 0; j < S; ++j) {
            int na = __builtin_amdgcn_readfirstlane(ipa[j]);
            fva[j] = fb32[(size_t)na * 64 + t];
        }
#pragma unroll
        for (int j = 0; j < S; ++j) {
            int nb = __builtin_amdgcn_readfirstlane(ipb[j]);
            fvb[j] = fb32[(size_t)nb * 64 + t];
        }
        float eva[S / 2], evb[S / 2];
#pragma unroll
        for (int e = 0; e < S / 2; ++e) {
            int a_ev = __builtin_amdgcn_readfirstlane(eixa[2 * e]);
            int a_od = __builtin_amdgcn_readfirstlane(eixa[2 * e + 1]);
            eva[e] = ee[(size_t)(hi ? a_od : a_ev) * E + t31];
        }
#pragma unroll
        for (int e = 0; e < S / 2; ++e) {
            int b_ev = __builtin_amdgcn_readfirstlane(eixb[2 * e]);
            int b_od = __builtin_amdgcn_readfirstlane(eixb[2 * e + 1]);
            evb[e] = ee[(size_t)(hi ? b_od : b_ev) * E + t31];
        }

        float sa0 = 0.f, sa1 = 0.f, sea = 0.f;
        float sb0 = 0.f, sb1 = 0.f, seb = 0.f;
#pragma unroll
        for (int j = 0; j < S; ++j) {
            sa0 += bf2f((unsigned short)(fva[j] & 0xFFFF));
            sa1 += bf2f((unsigned short)(fva[j] >> 16));
            sb0 += bf2f((unsigned short)(fvb[j] & 0xFFFF));
            sb1 += bf2f((unsigned short)(fvb[j] >> 16));
        }
#pragma unroll
        for (int e = 0; e < S / 2; ++e) { sea += eva[e]; seb += evb[e]; }
        sea += __shfl_xor(sea, 32);
        seb += __shfl_xor(seb, 32);

        ((unsigned int*)&Asm[lra][0])[t] = ava;
        ((unsigned int*)&Asm[lrb][0])[t] = avb;
        ((unsigned int*)&Nsm[lra][0])[t] =
            (unsigned int)f2bf(sa0 * inv) | ((unsigned int)f2bf(sa1 * inv) << 16);
        ((unsigned int*)&Nsm[lrb][0])[t] =
            (unsigned int)f2bf(sb0 * inv) | ((unsigned int)f2bf(sb1 * inv) << 16);
        if (t < E) {
            Nsm[lra][128 + t] = f2bf(sea * inv);
            Nsm[lrb][128 + t] = f2bf(seb * inv);
        }
    }
    __syncthreads();

    // ---- phase B: wave w computes n-tiles {2w, 2w+1} of the single m-tile ----
    const int q = t >> 4, lm = t & 15;
    const unsigned short* wb = WT0 + (size_t)mp * 2 * WSTRIDE;   // layer 0

    f4 acc[2];
    acc[0] = (f4){0.f, 0.f, 0.f, 0.f};
    acc[1] = (f4){0.f, 0.f, 0.f, 0.f};

#pragma unroll
    for (int kt = 0; kt < NKT; ++kt) {
        const int k0 = kt * 32 + q * 8;
        bh8 a = (k0 < 128) ? *(const bh8*)&Asm[lm][k0]
                           : *(const bh8*)&Nsm[lm][k0 - 128];
        const unsigned short* wrow = wb + ((size_t)(kt * 4 + q) * 128 + lm) * 8;
#pragma unroll
        for (int ntl = 0; ntl < 2; ++ntl) {
            bh8 bf = *(const bh8*)(wrow + (w * 2 + ntl) * 16 * 8);
            acc[ntl] = __builtin_amdgcn_mfma_f32_16x16x32_bf16(a, bf, acc[ntl], 0, 0, 0);
        }
    }

#pragma unroll
    for (int ntl = 0; ntl < 2; ++ntl)
#pragma unroll
        for (int rr = 0; rr < 4; ++rr) {
            int row = r0 + q * 4 + rr;             // C/D: col=lane&15, row=quad*4+reg
            int col = (w * 2 + ntl) * 16 + lm;
            fout[((size_t)mp * RPM + row) * 128 + col] = f2bf(fmaxf(acc[ntl][rr], 0.f));
        }
}

// ---------- fused edge GEMM + layer-1 mean -> agg1 [mp][B][160] bf16 ----------
// Edge rows never materialized: segment mean taken from MFMA accumulators.
__global__ __launch_bounds__(256) void edgeagg_k(
    const unsigned short* __restrict__ fout, const float* __restrict__ edge_emb,
    const int* __restrict__ eid1, const unsigned short* __restrict__ WTe,
    unsigned short* __restrict__ agg1)
{
    const int mp = blockIdx.y;
    const int w = threadIdx.x >> 6, l = threadIdx.x & 63;
    const int q = l >> 4, lm = l & 15;
    const int m0 = blockIdx.x * 128 + w * 32;          // wave: 2 m-tiles = 2 segments
    const unsigned short* we = WTe + (size_t)mp * WESTRIDE;
    const unsigned short* f1base = fout + (size_t)mp * RPM * 128;
    const unsigned short* f0base = fout + ((size_t)mp * RPM + 16384) * 128;
    const float* ee = edge_emb + (size_t)mp * NEDGE * E;
    const float inv = 1.0f / (float)S;

    const unsigned short* a1p[2];
    const unsigned short* a0p[2];
    int eidL[2];
#pragma unroll
    for (int mt = 0; mt < 2; ++mt) {
        int row = m0 + mt * 16 + lm;
        a1p[mt] = f1base + (size_t)row * 128;
        a0p[mt] = f0base + (size_t)(row >> 4) * 128;
        eidL[mt] = eid1[mp * 16384 + row];
    }

    f4 acc[2][2];
#pragma unroll
    for (int mt = 0; mt < 2; ++mt) { acc[mt][0] = (f4){0,0,0,0}; acc[mt][1] = (f4){0,0,0,0}; }

#pragma unroll
    for (int kt = 0; kt < NKT; ++kt) {
        const int k0 = kt * 32 + q * 8;
        bh8 a[2];
#pragma unroll
        for (int mt = 0; mt < 2; ++mt) {
            if (kt < 4) {
                a[mt] = *(const bh8*)(a0p[mt] + k0);
            } else if (kt < 8) {
                a[mt] = *(const bh8*)(a1p[mt] + (k0 - 128));
            } else {
                const float* ep = ee + (size_t)eidL[mt] * E + q * 8;
                float4 v0 = *(const float4*)ep;
                float4 v1 = *(const float4*)(ep + 4);
                bh8 tv;
                tv[0] = (short)f2bf(v0.x); tv[1] = (short)f2bf(v0.y);
                tv[2] = (short)f2bf(v0.z); tv[3] = (short)f2bf(v0.w);
                tv[4] = (short)f2bf(v1.x); tv[5] = (short)f2bf(v1.y);
                tv[6] = (short)f2bf(v1.z); tv[7] = (short)f2bf(v1.w);
                a[mt] = tv;
            }
        }
        const unsigned short* wrow = we + ((size_t)(kt * 4 + q) * 32 + lm) * 8;
        bh8 b0 = *(const bh8*)(wrow);
        bh8 b1 = *(const bh8*)(wrow + 16 * 8);
#pragma unroll
        for (int mt = 0; mt < 2; ++mt) {
            acc[mt][0] = __builtin_amdgcn_mfma_f32_16x16x32_bf16(a[mt], b0, acc[mt][0], 0, 0, 0);
            acc[mt][1] = __builtin_amdgcn_mfma_f32_16x16x32_bf16(a[mt], b1, acc[mt][1], 0, 0, 0);
        }
    }

    // edge part of agg1: mean over the 16 rows of each m-tile (one segment)
#pragma unroll
    for (int mt = 0; mt < 2; ++mt) {
        int seg = (m0 >> 4) + mt;
#pragma unroll
        for (int nt = 0; nt < 2; ++nt) {
            float ps = 0.f;
#pragma unroll
            for (int rr = 0; rr < 4; ++rr) ps += fmaxf(acc[mt][nt][rr], 0.f);
            ps += __shfl_xor(ps, 16);
            ps += __shfl_xor(ps, 32);                   // sum over quads -> full column sum
            if (l < 16)
                agg1[((size_t)mp * B + seg) * 160 + 128 + nt * 16 + lm] = f2bf(ps * inv);
        }
    }

    // f1 part of agg1: mean of fout level-1 rows for this wave's 2 segments
#pragma unroll
    for (int mt = 0; mt < 2; ++mt) {
        int seg = (m0 >> 4) + mt;
        const unsigned short* fr = f1base + (size_t)seg * 16 * 128;
        float s0 = 0.f, s1 = 0.f;
#pragma unroll
        for (int j = 0; j < S; ++j) {
            unsigned int u = ((const unsigned int*)(fr + j * 128))[l];
            s0 += bf2f((unsigned short)(u & 0xFFFF));
            s1 += bf2f((unsigned short)(u >> 16));
        }
        ((unsigned int*)(agg1 + ((size_t)mp * B + seg) * 160))[l] =
            (unsigned int)f2bf(s0 * inv) | ((unsigned int)f2bf(s1 * inv) << 16);
    }
}

// ---------- fused layer-1 GEMM (all 3 mps) + attention + normalize + fc ----------
// Block: 32 b-rows. LDS stages relu(GEMM) f32; then 8 threads/row finalize.
__global__ __launch_bounds__(256) void feat1fin_k(
    const unsigned short* __restrict__ fout, const unsigned short* __restrict__ agg1,
    const unsigned short* __restrict__ WT0,
    const float* __restrict__ attn, const float* __restrict__ fcw,
    const float* __restrict__ fcb, float* __restrict__ out)
{
    __shared__ float sbuf[NMP][32][132];                // +4 pad: conflict-free stores
    const int w = threadIdx.x >> 6, l = threadIdx.x & 63;
    const int q = l >> 4, lm = l & 15;
    const int m0 = blockIdx.x * 32;

    // tasks: (mp,mt) pairs; wave w does task w, waves 0,1 also task 4+w
    for (int task = w; task < 6; task += 4) {
        const int mp = task >> 1, mt = task & 1;
        const int row = m0 + mt * 16 + lm;              // < 1024
        const unsigned short* ap = fout + ((size_t)mp * RPM + 16384 + row) * 128;
        const unsigned short* np = agg1 + ((size_t)mp * B + row) * 160;
        const unsigned short* wb = WT0 + ((size_t)mp * 2 + 1) * WSTRIDE;

        f4 acc[8];
#pragma unroll
        for (int nt = 0; nt < 8; ++nt) acc[nt] = (f4){0.f, 0.f, 0.f, 0.f};
#pragma unroll
        for (int kt = 0; kt < NKT; ++kt) {
            const int k0 = kt * 32 + q * 8;
            bh8 a = (k0 < 128) ? *(const bh8*)(ap + k0) : *(const bh8*)(np + (k0 - 128));
            const unsigned short* wrow = wb + ((size_t)(kt * 4 + q) * 128 + lm) * 8;
#pragma unroll
            for (int nt = 0; nt < 8; ++nt) {
                bh8 bf = *(const bh8*)(wrow + nt * 16 * 8);
                acc[nt] = __builtin_amdgcn_mfma_f32_16x16x32_bf16(a, bf, acc[nt], 0, 0, 0);
            }
        }
#pragma unroll
        for (int nt = 0; nt < 8; ++nt)
#pragma unroll
            for (int rr = 0; rr < 4; ++rr)
                sbuf[mp][mt * 16 + q * 4 + rr][nt * 16 + lm] = fmaxf(acc[nt][rr], 0.f);
    }
    __syncthreads();

    // finalize: 8 threads per row, 16 dims each
    const int row = threadIdx.x >> 3;                   // [0,32)
    const int j = threadIdx.x & 7;
    const int d0 = j * 16;
    float sc[NMP];
#pragma unroll
    for (int mp = 0; mp < NMP; ++mp) {
        float p = 0.f;
#pragma unroll
        for (int d = 0; d < 16; ++d) p += sbuf[mp][row][d0 + d] * attn[d0 + d];
        p += __shfl_xor(p, 1); p += __shfl_xor(p, 2); p += __shfl_xor(p, 4);
        sc[mp] = tanhf(p);
    }
    float mx = fmaxf(sc[0], fmaxf(sc[1], sc[2]));
    float e0 = expf(sc[0] - mx), e1 = expf(sc[1] - mx), e2 = expf(sc[2] - mx);
    float isum = 1.f / (e0 + e1 + e2);
    float b0 = e0 * isum, b1 = e1 * isum, b2 = e2 * isum;

    float emb[16];
    float nn = 0.f;
#pragma unroll
    for (int d = 0; d < 16; ++d) {
        float v = b0 * sbuf[0][row][d0 + d] + b1 * sbuf[1][row][d0 + d]
                + b2 * sbuf[2][row][d0 + d];
        emb[d] = v;
        nn += v * v;
    }
    nn += __shfl_xor(nn, 1); nn += __shfl_xor(nn, 2); nn += __shfl_xor(nn, 4);
    float innorm = 1.f / fmaxf(sqrtf(nn), 1e-12f);
#pragma unroll
    for (int d = 0; d < 16; ++d) emb[d] *= innorm;

#pragma unroll
    for (int c = 0; c < NC; ++c) {
        float p = 0.f;
#pragma unroll
        for (int d = 0; d < 16; ++d) p += emb[d] * fcw[(d0 + d) * NC + c];
        p += __shfl_xor(p, 1); p += __shfl_xor(p, 2); p += __shfl_xor(p, 4);
        if (j == c) out[(size_t)(m0 + row) * NC + c] = p + fcb[c];
    }
}

extern "C" void kernel_launch(void* const* d_in, const int* in_sizes, int n_in,
                              void* d_out, int out_size, void* d_ws, size_t ws_size,
                              hipStream_t stream) {
    const int* ids        = (const int*)d_in[0];
    const float* feats    = (const float*)d_in[1];
    const float* edge_emb = (const float*)d_in[2];
    const int* adjn       = (const int*)d_in[3];
    const int* adje       = (const int*)d_in[4];
    const float* Ws       = (const float*)d_in[5];
    const float* Wn       = (const float*)d_in[6];
    const float* We       = (const float*)d_in[7];
    const float* attn     = (const float*)d_in[8];
    const float* fcw      = (const float*)d_in[9];
    const float* fcb      = (const float*)d_in[10];
    float* out = (float*)d_out;

    // workspace layout (~28 MB; all regions fully written before read each call)
    char* p = (char*)d_ws;
    unsigned short* WT0 = (unsigned short*)p; p += (size_t)6 * WSTRIDE * 2;
    unsigned short* WTe = (unsigned short*)p; p += (size_t)3 * WESTRIDE * 2;
    unsigned short* fb  = (unsigned short*)p; p += (size_t)NNODES * 128 * 2;
    int* gx   = (int*)p;                      p += (size_t)3 * RPM * 4;
    int* eid1 = (int*)p;                      p += (size_t)3 * 16384 * 4;
    unsigned short* fout = (unsigned short*)p; p += (size_t)3 * RPM * 128 * 2;
    unsigned short* agg1 = (unsigned short*)p; p += (size_t)3 * B * 160 * 2;

    convsamp_k<<<TOT_TASKS / 256, 256, 0, stream>>>(feats, Ws, Wn, We, ids, adjn, adje,
                                                    fb, WT0, WTe, gx, eid1);
    aggfeat_k<<<dim3(RPM / 16, 3), 256, 0, stream>>>(fb, edge_emb, adjn, adje, gx, eid1,
                                                     WT0, fout);
    edgeagg_k<<<dim3(128, 3), 256, 0, stream>>>(fout, edge_emb, eid1, WTe, agg1);
    feat1fin_k<<<32, 256, 0, stream>>>(fout, agg1, WT0, attn, fcw, fcb, out);
}